// Round 4
// baseline (227.701 us; speedup 1.0000x reference)
//
#include <hip/hip_runtime.h>

// Problem constants
#define B 16
#define S 4096
#define H 16
#define D 128
#define P 32768
#define HD (H * D)          // 2048 floats per page slab (8 KB)
#define NTOK (B * S)        // 65536
#define NVB (B * P)         // 524288 v-buckets

// ws layout (element offsets, 4-byte units)
#define O_HIST_K 0                        // P ints
#define O_HIST_V (O_HIST_K + P)           // B*P ints
#define O_EXCL_K (O_HIST_V + NVB)         // P ints
#define O_EXCL_V (O_EXCL_K + P)           // B*P ints (global positions)
#define O_CUR_K  (O_EXCL_V + NVB)         // P ints
#define O_CUR_V  (O_CUR_K + P)            // B*P ints
#define O_SRT_K  (O_CUR_V + NVB)          // NTOK u32
#define O_SRT_V  (O_SRT_K + NTOK)         // NTOK u32
#define O_E      (O_SRT_V + NTOK)         // NTOK*H floats (4 MB)
#define O_PART   (O_E + NTOK * H)         // 1024*2048 floats (8 MB)

#define SCALE 0.08838834764831845f        // 1/sqrt(128)

// ---- 1. histogram K pages and (b,V-page) buckets ----
__global__ __launch_bounds__(256) void hist_kernel(
    const int* __restrict__ kidx, const int* __restrict__ vidx, int* ws)
{
    const int g = blockIdx.x * 256 + threadIdx.x;   // 0..NTOK-1
    atomicAdd(ws + O_HIST_K + kidx[g], 1);
    const int b = g >> 12;
    atomicAdd(ws + O_HIST_V + b * P + vidx[g], 1);
}

// ---- 2. exclusive scans: 16 per-b V-hists + 1 K-hist (17 blocks x 1024) ----
__global__ __launch_bounds__(1024) void scan_kernel(int* ws)
{
    const int blk = blockIdx.x, t = threadIdx.x;
    const int* A;
    int *E, *C;
    int addbase;
    if (blk < 16) {
        A = ws + O_HIST_V + blk * P;
        E = ws + O_EXCL_V + blk * P;
        C = ws + O_CUR_V + blk * P;
        addbase = blk * S;                 // global positions within sortedV
    } else {
        A = ws + O_HIST_K; E = ws + O_EXCL_K; C = ws + O_CUR_K; addbase = 0;
    }
    const int base = t * 32;
    int s = 0;
    for (int i = 0; i < 32; ++i) s += A[base + i];
    __shared__ int sd[1024];
    sd[t] = s;
    __syncthreads();
    for (int d = 1; d < 1024; d <<= 1) {
        const int v = (t >= d) ? sd[t - d] : 0;
        __syncthreads();
        sd[t] += v;
        __syncthreads();
    }
    int run = sd[t] - s + addbase;         // exclusive prefix for this chunk
    for (int i = 0; i < 32; ++i) {
        E[base + i] = run;
        C[base + i] = run;
        run += A[base + i];
    }
}

// ---- 3. scatter entries into page-sorted lists ----
// entry = (page<<16) | (b<<12) | s  (page<=32767 -> fits, positive)
__global__ __launch_bounds__(256) void scatter_kernel(
    const int* __restrict__ kidx, const int* __restrict__ vidx, int* ws)
{
    const int g = blockIdx.x * 256 + threadIdx.x;
    const unsigned bs = (unsigned)(g & 0xFFFF);
    const int kp = kidx[g];
    int pos = atomicAdd(ws + O_CUR_K + kp, 1);
    ((unsigned*)(ws + O_SRT_K))[pos] = ((unsigned)kp << 16) | bs;
    const int b = g >> 12;
    const int vp = vidx[g];
    pos = atomicAdd(ws + O_CUR_V + b * P + vp, 1);
    ((unsigned*)(ws + O_SRT_V))[pos] = ((unsigned)vp << 16) | bs;
}

// ---- 4. determinize V buckets (sort each (b,page) bucket by s) ----
__global__ __launch_bounds__(256) void sortfix_kernel(int* ws)
{
    const int t = blockIdx.x * 256 + threadIdx.x;   // 0..NVB-1
    const int c = ws[O_HIST_V + t];
    if (c < 2) return;
    unsigned* L = (unsigned*)(ws + O_SRT_V) + ws[O_EXCL_V + t];
    for (int i = 1; i < c; ++i) {
        const unsigned key = L[i];
        int j = i - 1;
        while (j >= 0 && L[j] > key) { L[j + 1] = L[j]; --j; }
        L[j + 1] = key;
    }
}

// ---- 5. K pass: each referenced K-slab read exactly once grid-wide ----
// 1024 blocks x 256 thr; block j owns pages [j*32, (j+1)*32).
// thread (h=tid>>4, dc=tid&15) holds slab floats [h][dc*8..dc*8+7].
__global__ __launch_bounds__(256) void kpass_kernel(
    const float* __restrict__ q, const float* __restrict__ kv, int* ws)
{
    const unsigned* srt = (const unsigned*)(ws + O_SRT_K);
    const int* excl = ws + O_EXCL_K;
    float* e_ws = (float*)(ws + O_E);
    const int j = blockIdx.x;
    const int beg = excl[j * 32];
    const int end = (j == 1023) ? NTOK : excl[j * 32 + 32];
    if (beg >= end) return;
    const int tid = threadIdx.x, h = tid >> 4, dc = tid & 15;
    const int foff = h * D + dc * 8;

    int i = beg;
    int page = (int)(srt[i] >> 16);
    const float* sp = kv + (size_t)page * HD + foff;
    float4 na = *(const float4*)sp, nb = *(const float4*)(sp + 4);

    while (i < end) {
        // find run end of current page (uniform scalar loop, list is L1-hot)
        int j2 = i + 1;
        while (j2 < end && (int)(srt[j2] >> 16) == page) ++j2;
        const float4 ca = na, cb = nb;
        if (j2 < end) {                    // prefetch next distinct slab
            page = (int)(srt[j2] >> 16);
            const float* p2 = kv + (size_t)page * HD + foff;
            na = *(const float4*)p2; nb = *(const float4*)(p2 + 4);
        }
        for (int t = i; t < j2; ++t) {
            const unsigned bs = srt[t] & 0xFFFFu;
            const float* qp = q + ((bs >> 12) << 11) + foff;   // b*2048
            const float4 qa = *(const float4*)qp;
            const float4 qb = *(const float4*)(qp + 4);
            float dot = qa.x * ca.x + qa.y * ca.y + qa.z * ca.z + qa.w * ca.w +
                        qb.x * cb.x + qb.y * cb.y + qb.z * cb.z + qb.w * cb.w;
            dot += __shfl_xor(dot, 1);
            dot += __shfl_xor(dot, 2);
            dot += __shfl_xor(dot, 4);
            dot += __shfl_xor(dot, 8);
            if (dc == 0) e_ws[bs * 16 + h] = __expf(dot * SCALE);
        }
        i = j2;
    }
}

// ---- 6. V pass: per-b page-sorted accumulation into register partials ----
// 1024 blocks: b = blk>>6, range j = blk&63 -> pages [j*512,(j+1)*512).
__global__ __launch_bounds__(256) void vpass_kernel(
    const float* __restrict__ kv, int* ws)
{
    const float* vbase = kv + (size_t)P * HD;
    const unsigned* srt = (const unsigned*)(ws + O_SRT_V);
    const int* excl = ws + O_EXCL_V;
    const float* e_ws = (const float*)(ws + O_E);
    float* partial = (float*)(ws + O_PART);

    const int blk = blockIdx.x;
    const int b = blk >> 6, j = blk & 63;
    const int beg = excl[b * P + j * 512];
    const int end = (j == 63) ? (b + 1) * S : excl[b * P + (j + 1) * 512];
    const int tid = threadIdx.x, h = tid >> 4, dc = tid & 15;
    const int foff = h * D + dc * 8;

    float4 a0 = make_float4(0.f, 0.f, 0.f, 0.f);
    float4 a1 = make_float4(0.f, 0.f, 0.f, 0.f);

    if (beg < end) {
        int i = beg;
        unsigned ent = srt[i];
        int page = (int)(ent >> 16);
        const float* sp = vbase + (size_t)page * HD + foff;
        float4 na = *(const float4*)sp, nb = *(const float4*)(sp + 4);
        while (i < end) {
            const float4 ca = na, cb = nb;
            const unsigned cent = ent;
            const int nxt = i + 1;
            if (nxt < end) {
                ent = srt[nxt];
                const int np = (int)(ent >> 16);
                if (np != page) {
                    page = np;
                    const float* p2 = vbase + (size_t)np * HD + foff;
                    na = *(const float4*)p2; nb = *(const float4*)(p2 + 4);
                } else { na = ca; nb = cb; }   // duplicate page: reuse frag
            }
            const float ev = e_ws[(cent & 0xFFFFu) * 16 + h];
            a0.x += ev * ca.x; a0.y += ev * ca.y;
            a0.z += ev * ca.z; a0.w += ev * ca.w;
            a1.x += ev * cb.x; a1.y += ev * cb.y;
            a1.z += ev * cb.z; a1.w += ev * cb.w;
            i = nxt;
        }
    }
    float* pp = partial + (size_t)blk * 2048 + foff;
    *(float4*)pp = a0;
    *(float4*)(pp + 4) = a1;
}

// ---- 7. reduce: L[b,h] = sum_s e ; out = sum_j partial / L ----
__global__ __launch_bounds__(256) void reduce_kernel(
    const int* __restrict__ ws, float* __restrict__ out)
{
    const int b = blockIdx.x, t = threadIdx.x;
    const float* e_b = (const float*)(ws + O_E) + (size_t)b * (S * H);
    __shared__ float sd[256];
    __shared__ float Lh[16];
    float s = 0.f;
    for (int k = 0; k < 256; ++k) s += e_b[k * 256 + t];   // idx%16 == t%16
    sd[t] = s;
    __syncthreads();
    if (t < 16) {
        float L = 0.f;
        for (int g = 0; g < 16; ++g) L += sd[g * 16 + t];
        Lh[t] = L;
    }
    __syncthreads();

    const int o = t * 8;                 // h*128 + d, h = o>>7 uniform over 8
    const float inv = 1.f / Lh[o >> 7];
    const float* pb = (const float*)(ws + O_PART) + (size_t)b * 64 * 2048;
    float4 s0 = make_float4(0.f, 0.f, 0.f, 0.f);
    float4 s1 = make_float4(0.f, 0.f, 0.f, 0.f);
    for (int jj = 0; jj < 64; ++jj) {
        const float* pp = pb + jj * 2048 + o;
        const float4 p0 = *(const float4*)pp;
        const float4 p1 = *(const float4*)(pp + 4);
        s0.x += p0.x; s0.y += p0.y; s0.z += p0.z; s0.w += p0.w;
        s1.x += p1.x; s1.y += p1.y; s1.z += p1.z; s1.w += p1.w;
    }
    float* op = out + (size_t)b * 2048 + o;
    op[0] = s0.x * inv; op[1] = s0.y * inv; op[2] = s0.z * inv; op[3] = s0.w * inv;
    op[4] = s1.x * inv; op[5] = s1.y * inv; op[6] = s1.z * inv; op[7] = s1.w * inv;
}

extern "C" void kernel_launch(void* const* d_in, const int* in_sizes, int n_in,
                              void* d_out, int out_size, void* d_ws, size_t ws_size,
                              hipStream_t stream) {
    const float* q    = (const float*)d_in[0];
    const float* kv   = (const float*)d_in[1];
    const int*   kidx = (const int*)d_in[2];
    const int*   vidx = (const int*)d_in[3];
    float*       out  = (float*)d_out;
    int*         ws   = (int*)d_ws;

    // zero the two histograms (contiguous at ws start)
    hipMemsetAsync(ws, 0, (size_t)(P + NVB) * 4, stream);
    hist_kernel   <<<NTOK / 256, 256, 0, stream>>>(kidx, vidx, ws);
    scan_kernel   <<<17, 1024, 0, stream>>>(ws);
    scatter_kernel<<<NTOK / 256, 256, 0, stream>>>(kidx, vidx, ws);
    sortfix_kernel<<<NVB / 256, 256, 0, stream>>>(ws);
    kpass_kernel  <<<1024, 256, 0, stream>>>(q, kv, ws);
    vpass_kernel  <<<1024, 256, 0, stream>>>(kv, ws);
    reduce_kernel <<<16, 256, 0, stream>>>(ws, out);
}